// Round 1
// baseline (124.143 us; speedup 1.0000x reference)
//
#include <hip/hip_runtime.h>
#include <hip/hip_bf16.h>

#define N_Q   25000
#define M_S   25000
#define H_NB  32
#define K_KP  15
#define C_INV 128
#define C_OUTV 128

typedef unsigned short ushortT;
typedef unsigned short us8 __attribute__((ext_vector_type(8)));
typedef unsigned short us4 __attribute__((ext_vector_type(4)));
typedef short s8v __attribute__((ext_vector_type(8)));
typedef float f32x4 __attribute__((ext_vector_type(4)));

__device__ __forceinline__ float b2f(ushortT u) {
    unsigned v = ((unsigned)u) << 16;
    return __builtin_bit_cast(float, v);
}
__device__ __forceinline__ ushortT f2b(float f) {
    __hip_bfloat16 h = __float2bfloat16(f);
    return __builtin_bit_cast(ushortT, h);
}

// ---------------- kernel 1: x fp32 -> bf16 ----------------
__global__ void k_convert_x(const float* __restrict__ x, ushortT* __restrict__ xb) {
    int i = blockIdx.x * 256 + threadIdx.x;           // groups of 4
    const int n4 = (M_S * C_INV) / 4;                 // 800000
    if (i >= n4) return;
    float4 v = ((const float4*)x)[i];
    us4 o;
    o[0] = f2b(v.x); o[1] = f2b(v.y); o[2] = f2b(v.z); o[3] = f2b(v.w);
    ((us4*)xb)[i] = o;
}

// ---------------- kernel 2: W fp32 -> fragment-major bf16 ----------------
// Output elem o = (((kstep*8 + db)*64 + lane)*8 + j)
// holds Wflat[kstep*32 + (lane>>4)*8 + j][db*16 + (lane&15)], Wflat row = k*128+c.
__global__ void k_build_wfrag(const float* __restrict__ W, ushortT* __restrict__ wf) {
    int o = blockIdx.x * 256 + threadIdx.x;
    if (o >= 1920 * 128) return;
    int j  = o & 7;
    int l  = (o >> 3) & 63;
    int db = (o >> 9) & 7;
    int ks = o >> 12;
    int r  = ks * 32 + ((l >> 4) * 8) + j;   // kc index, < 1920
    int d  = db * 16 + (l & 15);
    wf[o] = f2b(W[r * 128 + d]);
}

// ---------------- kernel 3: fused main ----------------
__global__ __launch_bounds__(256, 2) void k_main(
    const float* __restrict__ qp, const float* __restrict__ sp,
    const int* __restrict__ nb, const float* __restrict__ kp,
    const ushortT* __restrict__ xbf, const ushortT* __restrict__ wfrag,
    float* __restrict__ out)
{
    __shared__ ushortT s_w[16][32][16];                    // 16 KiB, k=15 padded to 16 (pad=0)
    __shared__ int s_idx[16][32];                          // 2 KiB
    __shared__ __align__(16) ushortT s_wf[16][1928];       // 60.25 KiB, row pad 8 -> 2-way banks

    const int t   = threadIdx.x;
    const int blk = blockIdx.x;

    // ---- Stage A: influences w[q][k][h] ----
    {
        const int q  = t >> 4;
        const int h0 = t & 15;
        const int qg = blk * 16 + q;
        const int qc = (qg < N_Q) ? qg : 0;
        const float qx = qp[qc * 3 + 0], qy = qp[qc * 3 + 1], qz = qp[qc * 3 + 2];
        #pragma unroll
        for (int i = 0; i < 2; ++i) {
            const int h  = h0 + 16 * i;
            int idx = (qg < N_Q) ? nb[qg * H_NB + h] : M_S;
            const bool valid = ((unsigned)idx < (unsigned)M_S);   // idx==M is shadow
            s_idx[q][h] = valid ? idx : 0;                        // safe gather row; w=0 kills it
            float px, py, pz;
            if (valid) { px = sp[idx * 3]; py = sp[idx * 3 + 1]; pz = sp[idx * 3 + 2]; }
            else       { px = 1e6f; py = 1e6f; pz = 1e6f; }
            const float rx = px - qx, ry = py - qy, rz = pz - qz;
            #pragma unroll
            for (int k = 0; k < 15; ++k) {
                const float dx = rx - kp[k * 3 + 0];
                const float dy = ry - kp[k * 3 + 1];
                const float dz = rz - kp[k * 3 + 2];
                const float d2 = dx * dx + dy * dy + dz * dz;
                float w = 1.0f - sqrtf(d2) * (1.0f / 1.2f);
                w = (w > 0.0f) ? w : 0.0f;                        // shadow -> large d -> 0
                s_w[q][h][k] = f2b(w);
            }
            s_w[q][h][15] = 0;
        }
    }
    __syncthreads();

    // ---- Stage B: wf[q][k][c] = sum_h w[q][k][h] * x[idx[h]][c]  (fp32 VALU) ----
    {
        const int q  = t >> 4;
        const int c0 = (t & 15) * 8;
        float acc[15][8];
        #pragma unroll
        for (int k = 0; k < 15; ++k)
            #pragma unroll
            for (int j = 0; j < 8; ++j) acc[k][j] = 0.0f;

        int idx0 = s_idx[q][0];
        us8 xv = *(const us8*)(xbf + (size_t)idx0 * C_INV + c0);
        for (int h = 0; h < 32; ++h) {
            const us8 xc = xv;
            if (h < 31) {
                int idn = s_idx[q][h + 1];
                xv = *(const us8*)(xbf + (size_t)idn * C_INV + c0);
            }
            const us8 w0 = *(const us8*)&s_w[q][h][0];
            const us8 w1 = *(const us8*)&s_w[q][h][8];
            float xf[8];
            #pragma unroll
            for (int j = 0; j < 8; ++j) xf[j] = b2f(xc[j]);
            #pragma unroll
            for (int k = 0; k < 15; ++k) {
                const float wk = b2f((k < 8) ? w0[k] : w1[k - 8]);
                #pragma unroll
                for (int j = 0; j < 8; ++j) acc[k][j] += wk * xf[j];
            }
        }
        #pragma unroll
        for (int k = 0; k < 15; ++k) {
            us8 o;
            #pragma unroll
            for (int j = 0; j < 8; ++j) o[j] = f2b(acc[k][j]);
            *(us8*)&s_wf[q][k * C_INV + c0] = o;
        }
    }
    __syncthreads();

    // ---- Stage C: out[q][d] = sum_kc wf[q][kc] * W[kc][d] via MFMA 16x16x32 ----
    {
        const int lane = t & 63;
        const int wv   = t >> 6;
        const int db0  = wv * 2;
        const int arow = lane & 15;
        const int kofs = (lane >> 4) * 8;
        f32x4 acc0 = {0.f, 0.f, 0.f, 0.f};
        f32x4 acc1 = {0.f, 0.f, 0.f, 0.f};
        #pragma unroll 4
        for (int ks = 0; ks < 60; ++ks) {
            s8v a  = *(const s8v*)&s_wf[arow][ks * 32 + kofs];
            s8v b0 = *(const s8v*)(wfrag + ((size_t)(ks * 8 + db0) * 64 + lane) * 8);
            s8v b1 = *(const s8v*)(wfrag + ((size_t)(ks * 8 + db0 + 1) * 64 + lane) * 8);
            acc0 = __builtin_amdgcn_mfma_f32_16x16x32_bf16(a, b0, acc0, 0, 0, 0);
            acc1 = __builtin_amdgcn_mfma_f32_16x16x32_bf16(a, b1, acc1, 0, 0, 0);
        }
        #pragma unroll
        for (int r = 0; r < 4; ++r) {
            const int q  = (lane >> 4) * 4 + r;
            const int qg = blk * 16 + q;
            if (qg < N_Q) {
                out[(size_t)qg * C_OUTV + db0 * 16 + (lane & 15)]       = acc0[r];
                out[(size_t)qg * C_OUTV + (db0 + 1) * 16 + (lane & 15)] = acc1[r];
            }
        }
    }
}

extern "C" void kernel_launch(void* const* d_in, const int* in_sizes, int n_in,
                              void* d_out, int out_size, void* d_ws, size_t ws_size,
                              hipStream_t stream) {
    const float* x  = (const float*)d_in[0];
    const float* qp = (const float*)d_in[1];
    const float* sp = (const float*)d_in[2];
    const int*   nb = (const int*)d_in[3];
    const float* kp = (const float*)d_in[4];
    const float* W  = (const float*)d_in[5];
    float* out = (float*)d_out;

    ushortT* xbf   = (ushortT*)d_ws;                                  // 6.4 MB
    ushortT* wfrag = (ushortT*)((char*)d_ws + (size_t)M_S * C_INV * 2); // 491 KB

    k_convert_x<<<3125, 256, 0, stream>>>(x, xbf);
    k_build_wfrag<<<960, 256, 0, stream>>>(W, wfrag);

    const int nblk = (N_Q + 15) / 16;   // 1563
    k_main<<<nblk, 256, 0, stream>>>(qp, sp, nb, kp, xbf, wfrag, out);
}